// Round 10
// baseline (181.703 us; speedup 1.0000x reference)
//
#include <hip/hip_runtime.h>
#include <hip/hip_bf16.h>

// IsolaCLIPLoss: out = 3*align + 0.5*(log-mean-exp uniformity of img Gram + txt Gram)
// N=8192, D=512 fp32 inputs.
//
// R22: PROBE ROUND (R21 pre-commit triggered: total >=110 => spill theory
// false => surface gram's counters with a REP probe before any edit).
// State of evidence: seven structures (LDS/barrier x4, direct-uncoal 68us,
// direct-coal x2 launch-bounds) all land ~40-44us. Bottom-up models give
// 8-15us (MFMA busy 6.5us; L2 266-532MB = 8-15us; per-block chain ~6us/CU).
// Model vs measurement disagree 3x => need gram's own counters; it has
// been sub-fill (invisible) for 3 rounds.
// Design: normalize/gram/finalize byte-identical to R21 (gram templated
// <REP>, real launch REP=1). One probe dispatch AFTER finalize:
// gram<4> -> scratch S, "memory" clobber between reps blocks load-CSE.
// Probe ~160us > fill 45 => probe owns top-5 with full counters.
// Pre-registered readout:
//   per-rep=probe/4 ~40 => in-kernel cost confirmed; <<40 => dispatch/
//     cold-L2 artifact => fuse/warm next.
//   MfmaUtil<20% & VALUBusy<30% & Occ>=35% => VMEM latency => deepen window.
//   Occ ~19% => register pressure => shrink windows.
//   VALUBusy>50% => hidden VALU (accvgpr/addr) => disasm-driven fix.
//   FETCH >> 64MB => L2 thrash => XCD swizzle (T1).
// Predict: total 270-290us (diagnostic), passed, absmax 0.

#define NROWS 8192
#define NTRI  2080         // 64*65/2 upper-tri 128x128 tiles per matrix
#define SCALE4 0x7B7B7B7B  // E8M0 byte 123 = 2^-4, splatted

// fragment-major fp4 layout: row group rg = row>>5 (256 groups), chunk
// c = 0..15 (16B = 32 elems, c = 2*kk + h), row-in-group lr = row&31.
// byte address = rg*8192 + c*512 + lr*16. Total 2 MB per matrix.

typedef __attribute__((ext_vector_type(8)))  int   int8v;
typedef __attribute__((ext_vector_type(4)))  int   int4v;
typedef __attribute__((ext_vector_type(16))) float float16v;

// e2m1 code for x (already scaled): grid {0,.5,1,1.5,2,3,4,6}, RTNE midpoints.
__device__ inline unsigned fp4_code(float x) {
    const float a = fabsf(x);
    unsigned c = (a < 0.25f) ? 0u : (a < 0.75f) ? 1u : (a < 1.25f) ? 2u :
                 (a < 1.75f) ? 3u : (a < 2.5f)  ? 4u : (a < 3.5f)  ? 5u :
                 (a < 5.0f)  ? 6u : 7u;
    return c | ((__float_as_uint(x) >> 28) & 8u);
}

// ---------------------------------------------------------------- normalize
// UNCHANGED from R21.
__global__ __launch_bounds__(256) void normalize_kernel(
    const float* __restrict__ img, const float* __restrict__ txt,
    int* __restrict__ nimg, int* __restrict__ ntxt,   // fp4 fragment-major
    float* __restrict__ alignp,   // [2048] per-block partial of sum_i ndot_i
    float* __restrict__ S)        // [64] gram accumulators -> zeroed here
{
    if (blockIdx.x == 0 && threadIdx.x < 64) S[threadIdx.x] = 0.0f;

    const int lane = threadIdx.x & 63;
    const int wave = threadIdx.x >> 6;
    const int row  = blockIdx.x * 4 + wave;

    const float4* pi = (const float4*)(img + (size_t)row * 512);
    const float4* pt = (const float4*)(txt + (size_t)row * 512);
    const float4 i0 = pi[2 * lane], i1 = pi[2 * lane + 1];   // elems 8L..8L+7
    const float4 t0 = pt[2 * lane], t1 = pt[2 * lane + 1];

    float ssi = i0.x*i0.x + i0.y*i0.y + i0.z*i0.z + i0.w*i0.w
              + i1.x*i1.x + i1.y*i1.y + i1.z*i1.z + i1.w*i1.w;
    float sst = t0.x*t0.x + t0.y*t0.y + t0.z*t0.z + t0.w*t0.w
              + t1.x*t1.x + t1.y*t1.y + t1.z*t1.z + t1.w*t1.w;
    float dot = i0.x*t0.x + i0.y*t0.y + i0.z*t0.z + i0.w*t0.w
              + i1.x*t1.x + i1.y*t1.y + i1.z*t1.z + i1.w*t1.w;

    #pragma unroll
    for (int off = 1; off < 64; off <<= 1) {
        ssi += __shfl_xor(ssi, off);
        sst += __shfl_xor(sst, off);
        dot += __shfl_xor(dot, off);
    }
    const float inv_i = 1.0f / fmaxf(sqrtf(ssi), 1e-12f);
    const float inv_t = 1.0f / fmaxf(sqrtf(sst), 1e-12f);
    const float si = 16.0f * inv_i;   // quantize at 2^4 scale
    const float st = 16.0f * inv_t;

    unsigned wi = 0, wt = 0;
    wi |= fp4_code(i0.x * si)       | (fp4_code(i0.y * si) << 4)
       |  (fp4_code(i0.z * si) << 8)| (fp4_code(i0.w * si) << 12)
       |  (fp4_code(i1.x * si) <<16)| (fp4_code(i1.y * si) << 20)
       |  (fp4_code(i1.z * si) <<24)| (fp4_code(i1.w * si) << 28);
    wt |= fp4_code(t0.x * st)       | (fp4_code(t0.y * st) << 4)
       |  (fp4_code(t0.z * st) << 8)| (fp4_code(t0.w * st) << 12)
       |  (fp4_code(t1.x * st) <<16)| (fp4_code(t1.y * st) << 20)
       |  (fp4_code(t1.z * st) <<24)| (fp4_code(t1.w * st) << 28);

    const int idx = ((row >> 5) << 11) + ((lane >> 2) << 7)
                  + ((row & 31) << 2) + (lane & 3);
    nimg[idx] = (int)wi;
    ntxt[idx] = (int)wt;

    __shared__ float r4[4];
    if (lane == 0) r4[wave] = dot * inv_i * inv_t;
    __syncthreads();
    if (threadIdx.x == 0)
        alignp[blockIdx.x] = r4[0] + r4[1] + r4[2] + r4[3];
}

// ---------------------------------------------------------------- gram + lme
// Structure byte-identical to R21; REP wraps the whole job (addresses are
// rep-invariant; "memory" clobber blocks cross-rep load CSE). REP=1 is the
// real kernel; REP=4 is the counter-surfacing probe.
template<int REP>
__global__ __launch_bounds__(256, 2) void gram_kernel(
    const unsigned char* __restrict__ A0,   // fp4 img, fragment-major, 2 MB
    const unsigned char* __restrict__ A1,   // fp4 txt
    float* __restrict__ S)                  // [64] spread accumulators
{
    const int tid  = threadIdx.x;
    const int lane = tid & 63;
    const int wave = tid >> 6;
    const int wm = wave & 1, wn = wave >> 1;

    // decode tt -> (i,j): cum(i) = 64i - i(i-1)/2
    const int tt = blockIdx.x;
    int i = (int)((129.0f - sqrtf(16641.0f - 8.0f * (float)tt)) * 0.5f);
    while (64 * (i + 1) - ((i + 1) * i) / 2 <= tt) ++i;
    while (64 * i - (i * (i - 1)) / 2 > tt) --i;
    const int j = i + (tt - (64 * i - (i * (i - 1)) / 2));

    const unsigned char* __restrict__ M = blockIdx.y ? A1 : A0;

    // row-group bases: rg = (tilebase + half*64 + mt*32) >> 5
    const unsigned char* a0p = M + ((size_t)(i * 4 + wm * 2)) * 8192 + lane * 16;
    const unsigned char* a1p = a0p + 8192;
    const unsigned char* b0p = M + ((size_t)(j * 4 + wn * 2)) * 8192 + lane * 16;
    const unsigned char* b1p = b0p + 8192;

    float16v acc[2][2];
    #pragma unroll
    for (int a = 0; a < 2; ++a)
        #pragma unroll
        for (int c = 0; c < 2; ++c)
            #pragma unroll
            for (int r = 0; r < 16; ++r) acc[a][c][r] = 0.0f;

    // Operand windows: upper 4 ints permanently zero (fp4 in low 4 ints;
    // cbsz=blgp=4). Loads overwrite only the low int4v.
    int8v a0w[2], a1w[2], b0w[2], b1w[2];
    #pragma unroll
    for (int q = 0; q < 2; ++q) {
        a0w[q] = (int8v){0,0,0,0,0,0,0,0};
        a1w[q] = (int8v){0,0,0,0,0,0,0,0};
        b0w[q] = (int8v){0,0,0,0,0,0,0,0};
        b1w[q] = (int8v){0,0,0,0,0,0,0,0};
    }

    for (int rep = 0; rep < REP; ++rep) {
        if constexpr (REP > 1) asm volatile("" ::: "memory");
        // prime kk=0 into window 0
        *(int4v*)&a0w[0] = *(const int4v*)(a0p);
        *(int4v*)&a1w[0] = *(const int4v*)(a1p);
        *(int4v*)&b0w[0] = *(const int4v*)(b0p);
        *(int4v*)&b1w[0] = *(const int4v*)(b1p);

        #pragma unroll
        for (int kk = 0; kk < 8; ++kk) {       // 8 K=64 steps (full D=512)
            const int w = kk & 1;
            if (kk < 7) {                      // prefetch kk+1 into w^1
                const int off = (kk + 1) << 10;    // +1024B per kk
                *(int4v*)&a0w[w ^ 1] = *(const int4v*)(a0p + off);
                *(int4v*)&a1w[w ^ 1] = *(const int4v*)(a1p + off);
                *(int4v*)&b0w[w ^ 1] = *(const int4v*)(b0p + off);
                *(int4v*)&b1w[w ^ 1] = *(const int4v*)(b1p + off);
            }
            acc[0][0] = __builtin_amdgcn_mfma_scale_f32_32x32x64_f8f6f4(
                a0w[w], b0w[w], acc[0][0], 4, 4, 0, SCALE4, 0, SCALE4);
            acc[0][1] = __builtin_amdgcn_mfma_scale_f32_32x32x64_f8f6f4(
                a0w[w], b1w[w], acc[0][1], 4, 4, 0, SCALE4, 0, SCALE4);
            acc[1][0] = __builtin_amdgcn_mfma_scale_f32_32x32x64_f8f6f4(
                a1w[w], b0w[w], acc[1][0], 4, 4, 0, SCALE4, 0, SCALE4);
            acc[1][1] = __builtin_amdgcn_mfma_scale_f32_32x32x64_f8f6f4(
                a1w[w], b1w[w], acc[1][1], 4, 4, 0, SCALE4, 0, SCALE4);
        }
    }

    // Epilogue: exp-fold with symmetry weight (2 off-diag, 1 diag tile;
    // true diagonal g=1 handled exactly by the fmin clamp). For REP>1 the
    // acc holds REP x the dot -> clamp still bounds it; output is scratch.
    const float wgt = (j > i) ? 2.0f : 1.0f;
    float f = 0.0f;
    #pragma unroll
    for (int mt = 0; mt < 2; ++mt)
        #pragma unroll
        for (int nt = 0; nt < 2; ++nt)
            #pragma unroll
            for (int r2 = 0; r2 < 16; ++r2) {
                const float g = acc[mt][nt][r2];
                f += __expf(4.0f * fminf(g, 1.0f) - 4.0f);
            }
    f *= wgt;
    #pragma unroll
    for (int off = 32; off; off >>= 1) f += __shfl_down(f, off);

    __shared__ float ps[4];
    if (lane == 0) ps[wave] = f;
    __syncthreads();
    if (tid == 0)
        atomicAdd(&S[blockIdx.y * 32 + (blockIdx.x & 31)],
                  ps[0] + ps[1] + ps[2] + ps[3]);
}

// ---------------------------------------------------------------- finalize
__global__ __launch_bounds__(256) void finalize_kernel(
    const float* __restrict__ S,       // [64]
    const float* __restrict__ alignp,  // [2048]
    float* __restrict__ out)
{
    const int tid = threadIdx.x;
    float a = 0.0f;
    #pragma unroll
    for (int k = 0; k < 8; ++k) a += alignp[tid + 256 * k];
    #pragma unroll
    for (int off = 32; off; off >>= 1) a += __shfl_down(a, off);
    __shared__ float r4[4];
    if ((tid & 63) == 0) r4[tid >> 6] = a;
    __syncthreads();
    if (tid == 0) {
        const double A = (double)r4[0] + r4[1] + r4[2] + r4[3];
        double si = 0.0, st = 0.0;
        for (int k = 0; k < 32; ++k) { si += S[k]; st += S[32 + k]; }
        const double align = 2.0 - 2.0 * A / (double)NROWS;
        const double n2 = (double)NROWS * (double)NROWS;
        const double unif = 0.5 * (log(si / n2) + log(st / n2));
        out[0] = (float)(3.0 * align + unif);
    }
}

// ---------------------------------------------------------------- launch
extern "C" void kernel_launch(void* const* d_in, const int* in_sizes, int n_in,
                              void* d_out, int out_size, void* d_ws, size_t ws_size,
                              hipStream_t stream) {
    const float* img = (const float*)d_in[0];
    const float* txt = (const float*)d_in[1];
    char* ws = (char*)d_ws;
    int* nimg = (int*)ws;                                        // 2 MB fp4
    int* ntxt = (int*)(ws + (size_t)NROWS * 256);                // 2 MB fp4
    float* S      = (float*)(ws + 2 * (size_t)NROWS * 256);      // [64]
    float* alignp = S + 64;                                      // [2048]
    float* Sdummy = alignp + 2048;                               // probe sink

    normalize_kernel<<<NROWS / 4, 256, 0, stream>>>(img, txt, nimg, ntxt, alignp, S);
    gram_kernel<1><<<dim3(NTRI, 2), 256, 0, stream>>>(
        (const unsigned char*)nimg, (const unsigned char*)ntxt, S);
    finalize_kernel<<<1, 256, 0, stream>>>(S, alignp, (float*)d_out);
    // --- counter-surfacing probe (scratch output, after the real pipeline)
    gram_kernel<4><<<dim3(NTRI, 2), 256, 0, stream>>>(
        (const unsigned char*)nimg, (const unsigned char*)ntxt, Sdummy);
}